// Round 2
// baseline (269.834 us; speedup 1.0000x reference)
//
#include <hip/hip_runtime.h>
#include <math.h>

// Problem constants (from reference):
//   N_WIDTH=128, N_ORDER=4, N_ELEMENTS=128, N_NODES=513, X in [0,1]
//   delta = 1/256  ->  1/delta = 256, 1/delta^2 = 65536
// Output: [3, 1, 128, 513] f32 = buffer slices at [sample] with 5 columns/row
// patched with Lagrange p / dp/delta / ddp/delta^2. x scalar -> same columns
// and values for every row.
//
// R1 note: bench dur_us (267 µs) is dominated by harness reset fills
// (3 × ~540 MB @ 87% HBM peak, seen in rocprof). This kernel is ~5 µs of it.
// R2: float4 pass-through (4× fewer mem instrs, 193 vs 770 blocks) as a
// hypothesis test that dur_us is harness-bound.

#define PHI_W     128
#define PHI_NN    513
#define PHI_ORD   4
#define PHI_PER   (PHI_W * PHI_NN)      /* 65664, %4==0 */
#define PHI_TOTAL (3 * PHI_PER)         /* 196992 */
#define PHI_VEC   (PHI_TOTAL / 4)       /* 49248 float4s */

// Lagrange basis value / scaled 1st / scaled 2nd derivative at local coord xt
// for basis index j (0..4), buffer kind k (0=p, 1=dp/delta, 2=ddp/delta^2).
__device__ __forceinline__ float phi_val(int k, int j, float xt) {
    // nodes = linspace(-1,1,5): nodes[m] = -1 + 0.5*m
    float nj = -1.0f + 0.5f * (float)j;
    float ratio[5];   // (xt-nodes[m])/(nodes[j]-nodes[m]); ratio[j]=1
    float invjm[5];   // 1/(nodes[j]-nodes[m]); invjm[j]=0
    #pragma unroll
    for (int m = 0; m < 5; ++m) {
        float nm = -1.0f + 0.5f * (float)m;
        if (m == j) { ratio[m] = 1.0f; invjm[m] = 0.0f; }
        else {
            float inv = 1.0f / (nj - nm);
            invjm[m] = inv;
            ratio[m] = (xt - nm) * inv;
        }
    }
    if (k == 0) {
        float p = 1.0f;
        #pragma unroll
        for (int m = 0; m < 5; ++m) p *= ratio[m];
        return p;
    } else if (k == 1) {
        float dp = 0.0f;
        #pragma unroll
        for (int i = 0; i < 5; ++i) {
            if (i == j) continue;
            float pr = 1.0f;
            #pragma unroll
            for (int m = 0; m < 5; ++m)
                if (m != i) pr *= ratio[m];     // ratio[j]==1 excludes j
            dp += invjm[i] * pr;
        }
        return dp * 256.0f;                     // dp / delta
    } else {
        float ddp = 0.0f;
        #pragma unroll
        for (int i = 0; i < 5; ++i) {
            if (i == j) continue;
            float inner = 0.0f;
            #pragma unroll
            for (int m = 0; m < 5; ++m) {
                if (m == i || m == j) continue;
                float pr = 1.0f;
                #pragma unroll
                for (int n = 0; n < 5; ++n)
                    if (n != i && n != m) pr *= ratio[n];
                inner += invjm[m] * pr;
            }
            ddp += invjm[i] * inner;
        }
        return ddp * 65536.0f;                  // ddp / delta^2
    }
}

__global__ __launch_bounds__(256) void phi_kernel(
    const float* __restrict__ x_ptr,
    const float* __restrict__ phi_in,
    const float* __restrict__ dphi_in,
    const float* __restrict__ ddphi_in,
    const int*   __restrict__ sample_ptr,
    float*       __restrict__ out)
{
    int f = blockIdx.x * blockDim.x + threadIdx.x;
    if (f >= PHI_VEC) return;

    int e   = f * 4;                    // flat element index
    int k   = e / PHI_PER;              // 0=phi, 1=dphi, 2=ddphi (no x-over: PHI_PER%4==0)
    int rem = e - k * PHI_PER;          // w*513 + c, %4==0

    int sample = sample_ptr[0];
    const float* buf = (k == 0) ? phi_in : ((k == 1) ? dphi_in : ddphi_in);
    // base + sample*PHI_PER + rem is 16B-aligned (all terms %4==0, base 16B)
    float4 v = *reinterpret_cast<const float4*>(buf + (size_t)sample * PHI_PER + rem);

    // Scalar-x element math (wave-uniform)
    float x       = x_ptr[0];
    float x_shift = 512.0f * x;
    int   id_el   = min(max((int)floorf(x_shift * 0.25f), 0), 127);
    int   nodes_l = id_el * PHI_ORD;
    float xt      = (x_shift - (float)(nodes_l + 2)) * 0.5f;

    int c0 = rem % PHI_NN;              // column of element 0 (may wrap row inside float4)
    float* vv = reinterpret_cast<float*>(&v);
    #pragma unroll
    for (int i = 0; i < 4; ++i) {
        int c = c0 + i;
        if (c >= PHI_NN) c -= PHI_NN;   // float4 crossing a row boundary
        int j = c - nodes_l;
        if ((unsigned)j <= 4u)          // ~1% of elements
            vv[i] = phi_val(k, j, xt);
    }
    reinterpret_cast<float4*>(out)[f] = v;
}

extern "C" void kernel_launch(void* const* d_in, const int* in_sizes, int n_in,
                              void* d_out, int out_size, void* d_ws, size_t ws_size,
                              hipStream_t stream) {
    (void)in_sizes; (void)n_in; (void)out_size; (void)d_ws; (void)ws_size;
    const float* x      = (const float*)d_in[0];
    const float* phi    = (const float*)d_in[1];
    const float* dphi   = (const float*)d_in[2];
    const float* ddphi  = (const float*)d_in[3];
    const int*   sample = (const int*)d_in[4];
    // d_in[5] = epoch, unused by the reference forward.
    float* out = (float*)d_out;

    const int threads = 256;
    const int blocks  = (PHI_VEC + threads - 1) / threads;   // 193
    phi_kernel<<<blocks, threads, 0, stream>>>(x, phi, dphi, ddphi, sample, out);
}